// Round 1
// baseline (1005.322 us; speedup 1.0000x reference)
//
#include <hip/hip_runtime.h>
#include <hip/hip_bf16.h>

// ---------- types ----------
typedef __attribute__((ext_vector_type(8))) short bf16x8;     // 8 bf16 = 4 VGPR (guide-verified frag type)
typedef __attribute__((ext_vector_type(4))) float f32x4;
typedef __attribute__((ext_vector_type(8))) unsigned short u16x8;

__device__ __forceinline__ unsigned short f2bf(float x) {
    union { float f; unsigned u; } v; v.f = x;
    unsigned r = v.u + 0x7fff + ((v.u >> 16) & 1);   // RNE
    return (unsigned short)(r >> 16);
}

__device__ __forceinline__ void gload16(const void* g, void* l) {
    __builtin_amdgcn_global_load_lds(
        (const __attribute__((address_space(1))) void*)g,
        (__attribute__((address_space(3))) void*)l, 16, 0, 0);
}

// ---------- cast fp32 -> bf16, 8 elems/thread ----------
__global__ __launch_bounds__(256) void cast_bf16_kernel(
    const float* __restrict__ src, unsigned short* __restrict__ dst, int n8) {
    int i = blockIdx.x * 256 + threadIdx.x;
    if (i >= n8) return;
    const float4* s = (const float4*)src + (size_t)i * 2;
    float4 a = s[0], b = s[1];
    u16x8 o;
    o[0] = f2bf(a.x); o[1] = f2bf(a.y); o[2] = f2bf(a.z); o[3] = f2bf(a.w);
    o[4] = f2bf(b.x); o[5] = f2bf(b.y); o[6] = f2bf(b.z); o[7] = f2bf(b.w);
    *(u16x8*)(dst + (size_t)i * 8) = o;
}

// ---------- transpose + cast: src fp32 [R][C] -> dst bf16 [C][R] ----------
__global__ __launch_bounds__(256) void transpose_cast_kernel(
    const float* __restrict__ src, unsigned short* __restrict__ dst, int R, int C) {
    __shared__ float tile[32][33];
    const int bx = blockIdx.x * 32, by = blockIdx.y * 32;
    const int tx = threadIdx.x & 31, ty = threadIdx.x >> 5;  // 32 x 8
#pragma unroll
    for (int i = 0; i < 32; i += 8)
        tile[ty + i][tx] = src[(size_t)(by + ty + i) * C + (bx + tx)];
    __syncthreads();
#pragma unroll
    for (int i = 0; i < 32; i += 8)
        dst[(size_t)(bx + ty + i) * R + (by + tx)] = f2bf(tile[tx][ty + i]);
}

// ---------- GEMM: C[M][N] = A[M][K](bf16) @ BT[N][K](bf16)^T ----------
// m97 structure: 128x128 tile, BK=32, dbuf LDS via global_load_lds(16B),
// 4 waves (2x2), each 64x64 out = 4x4 frags of 16x16x32 MFMA.
template <int OUTBF>
__global__ __launch_bounds__(256) void gemm_kernel(
    const unsigned short* __restrict__ A, const unsigned short* __restrict__ BT,
    void* __restrict__ Cp, int M, int N, int K) {
    __shared__ unsigned short Al[2][128 * 32];
    __shared__ unsigned short Bl[2][128 * 32];
    const int t = threadIdx.x;
    const int wid = t >> 6, lane = t & 63;
    const int l15 = lane & 15, lg = lane >> 4;
    const int bm = blockIdx.y * 128, bn = blockIdx.x * 128;
    const int wm = (wid >> 1) * 64, wn = (wid & 1) * 64;

    f32x4 acc[4][4];
#pragma unroll
    for (int i = 0; i < 4; ++i)
#pragma unroll
        for (int j = 0; j < 4; ++j) acc[i][j] = (f32x4)(0.f);

    const int nk = K >> 5;
    const int c0 = t, c1 = t + 256;

    auto stage = [&](int buf, int kt) {
        const unsigned short* Ab = A + (size_t)bm * K + kt * 32;
        const unsigned short* Bb = BT + (size_t)bn * K + kt * 32;
        // chunk c: row=c>>2, 16B piece (c&3); LDS linear [row][32]
        gload16(Ab + (size_t)(c0 >> 2) * K + (c0 & 3) * 8, &Al[buf][wid * 64 * 8]);
        gload16(Ab + (size_t)(c1 >> 2) * K + (c1 & 3) * 8, &Al[buf][(256 + wid * 64) * 8]);
        gload16(Bb + (size_t)(c0 >> 2) * K + (c0 & 3) * 8, &Bl[buf][wid * 64 * 8]);
        gload16(Bb + (size_t)(c1 >> 2) * K + (c1 & 3) * 8, &Bl[buf][(256 + wid * 64) * 8]);
    };

    stage(0, 0);
    __syncthreads();
    for (int kt = 0; kt < nk; ++kt) {
        const int cur = kt & 1;
        if (kt + 1 < nk) stage(cur ^ 1, kt + 1);
        bf16x8 af[4], bfr[4];
#pragma unroll
        for (int i = 0; i < 4; ++i) {
            af[i]  = *(const bf16x8*)&Al[cur][(wm + i * 16 + l15) * 32 + lg * 8];
            bfr[i] = *(const bf16x8*)&Bl[cur][(wn + i * 16 + l15) * 32 + lg * 8];
        }
#pragma unroll
        for (int i = 0; i < 4; ++i)
#pragma unroll
            for (int j = 0; j < 4; ++j)
                acc[i][j] = __builtin_amdgcn_mfma_f32_16x16x32_bf16(af[i], bfr[j], acc[i][j], 0, 0, 0);
        __syncthreads();
    }

#pragma unroll
    for (int i = 0; i < 4; ++i)
#pragma unroll
        for (int j = 0; j < 4; ++j)
#pragma unroll
            for (int r = 0; r < 4; ++r) {
                const int row = bm + wm + i * 16 + lg * 4 + r;
                const int col = bn + wn + j * 16 + l15;
                if (OUTBF) ((unsigned short*)Cp)[(size_t)row * N + col] = f2bf(acc[i][j][r]);
                else       ((float*)Cp)[(size_t)row * N + col] = acc[i][j][r];
            }
}

// ---------- flash attention (MQA, ALiBi, causal) ----------
// qkv bf16 [B*S][4352]; q at col h*128, k at 4096, v at 4224.
// block = 4 waves; wave w handles q rows qb*64 + w*16 .. +15; KV tile = 32.
__global__ __launch_bounds__(256) void attn_kernel(
    const unsigned short* __restrict__ qkv, unsigned short* __restrict__ attn, int S) {
    constexpr int LD = 4352;
    __shared__ unsigned short Kl[32 * 128];   // [krow][d], rows XOR-swizzled by ((row&7)<<4)
    __shared__ unsigned short Vt[128 * 32];   // V^T [dd][k], swizzled by ((dd&3)<<4)
    __shared__ unsigned short Pl[4][16 * 32]; // per-wave P, swizzled by ((row&3)<<4)
    const int t = threadIdx.x, wid = t >> 6, lane = t & 63;
    const int l15 = lane & 15, lg = lane >> 4;
    const int qb = blockIdx.x, h = blockIdx.y, b = blockIdx.z;
    const size_t rb = (size_t)b * S;
    const int q0 = qb * 64 + wid * 16;
    const float slope = exp2f(-0.25f * (float)(h + 1));
    const float scale = 0.08838834764831845f; // 1/sqrt(128)

    bf16x8 qf[4];
    {
        const unsigned short* qrow = qkv + (rb + q0 + l15) * LD + h * 128 + lg * 8;
#pragma unroll
        for (int j = 0; j < 4; ++j) qf[j] = *(const bf16x8*)(qrow + j * 32);
    }

    f32x4 o[8];
#pragma unroll
    for (int i = 0; i < 8; ++i) o[i] = (f32x4)(0.f);
    float m_[4], l_[4];
#pragma unroll
    for (int r = 0; r < 4; ++r) { m_[r] = -1e30f; l_[r] = 0.f; }

    const int ntile = qb * 2 + 2;
    for (int tile = 0; tile < ntile; ++tile) {
        const int t0 = tile * 32;
        // stage K: gload_lds, source pre-swizzled so swizzled reads see linear data
        {
            const char* kbase = (const char*)(qkv + (rb + t0) * LD + 4096);
#pragma unroll
            for (int i = 0; i < 2; ++i) {
                const int c = t + i * 256;
                const int row = c >> 4;
                const int off = ((c & 15) * 16) ^ ((row & 7) << 4);
                gload16(kbase + (size_t)row * (LD * 2) + off,
                        (char*)Kl + (i * 256 + wid * 64) * 16);
            }
        }
        // stage V^T via reg transpose
        {
            const int vk = t >> 3, vd0 = (t & 7) * 16;
            const unsigned short* vs = qkv + (rb + t0 + vk) * LD + 4224 + vd0;
            u16x8 v0 = *(const u16x8*)vs;
            u16x8 v1 = *(const u16x8*)(vs + 8);
#pragma unroll
            for (int e = 0; e < 8; ++e) {
                int dd = vd0 + e;
                *(unsigned short*)((char*)Vt + dd * 64 + ((2 * vk) ^ ((dd & 3) << 4))) = v0[e];
                dd += 8;
                *(unsigned short*)((char*)Vt + dd * 64 + ((2 * vk) ^ ((dd & 3) << 4))) = v1[e];
            }
        }
        __syncthreads();

        // scores: S = Q @ K^T   (two 16-col tiles)
        f32x4 s4[2];
#pragma unroll
        for (int ct = 0; ct < 2; ++ct) {
            s4[ct] = (f32x4)(0.f);
#pragma unroll
            for (int j = 0; j < 4; ++j) {
                const int row = ct * 16 + l15;
                bf16x8 kf = *(const bf16x8*)((const char*)Kl + row * 256 +
                                             ((j * 64 + lg * 16) ^ ((row & 7) << 4)));
                s4[ct] = __builtin_amdgcn_mfma_f32_16x16x32_bf16(qf[j], kf, s4[ct], 0, 0, 0);
            }
        }
        // online softmax (rows live on 16-lane groups; acc row = lg*4+r, col = l15)
        float corr[4];
#pragma unroll
        for (int r = 0; r < 4; ++r) {
            const int q = q0 + lg * 4 + r;
            const int kv0 = t0 + l15, kv1 = t0 + 16 + l15;
            float sc0 = (kv0 <= q) ? s4[0][r] * scale + slope * (float)(kv0 - q) : -1e30f;
            float sc1 = (kv1 <= q) ? s4[1][r] * scale + slope * (float)(kv1 - q) : -1e30f;
            float mx = fmaxf(sc0, sc1);
            mx = fmaxf(mx, __shfl_xor(mx, 1, 16));
            mx = fmaxf(mx, __shfl_xor(mx, 2, 16));
            mx = fmaxf(mx, __shfl_xor(mx, 4, 16));
            mx = fmaxf(mx, __shfl_xor(mx, 8, 16));
            const float mnew = fmaxf(m_[r], mx);
            corr[r] = __expf(m_[r] - mnew);
            m_[r] = mnew;
            float p0 = __expf(sc0 - mnew), p1 = __expf(sc1 - mnew);
            float rs = p0 + p1;
            rs += __shfl_xor(rs, 1, 16);
            rs += __shfl_xor(rs, 2, 16);
            rs += __shfl_xor(rs, 4, 16);
            rs += __shfl_xor(rs, 8, 16);
            l_[r] = l_[r] * corr[r] + rs;
            const int prow = lg * 4 + r;
            *(unsigned short*)((char*)&Pl[wid][0] + prow * 64 + ((2 * l15) ^ ((prow & 3) << 4))) = f2bf(p0);
            *(unsigned short*)((char*)&Pl[wid][0] + prow * 64 + ((2 * (16 + l15)) ^ ((prow & 3) << 4))) = f2bf(p1);
        }
        // PV: O += P @ V  (A-frag from Pl, B-frag from Vt)
        bf16x8 pa = *(const bf16x8*)((const char*)&Pl[wid][0] + l15 * 64 +
                                     ((lg * 16) ^ ((l15 & 3) << 4)));
#pragma unroll
        for (int n = 0; n < 8; ++n) {
            const int dd = n * 16 + l15;
            bf16x8 vf = *(const bf16x8*)((const char*)Vt + dd * 64 +
                                         ((lg * 16) ^ ((dd & 3) << 4)));
            f32x4 a4 = o[n];
            a4[0] *= corr[0]; a4[1] *= corr[1]; a4[2] *= corr[2]; a4[3] *= corr[3];
            o[n] = __builtin_amdgcn_mfma_f32_16x16x32_bf16(pa, vf, a4, 0, 0, 0);
        }
        __syncthreads();
    }
#pragma unroll
    for (int n = 0; n < 8; ++n)
#pragma unroll
        for (int r = 0; r < 4; ++r) {
            const int q = q0 + lg * 4 + r;
            const int col = h * 128 + n * 16 + l15;
            attn[(rb + q) * 4096 + col] = f2bf(o[n][r] / l_[r]);
        }
}

// ---------- launch ----------
extern "C" void kernel_launch(void* const* d_in, const int* in_sizes, int n_in,
                              void* d_out, int out_size, void* d_ws, size_t ws_size,
                              hipStream_t stream) {
    const float* hidden = (const float*)d_in[0];
    const float* Wqkv   = (const float*)d_in[1];
    const float* Wo     = (const float*)d_in[2];
    float* out = (float*)d_out;
    char* ws = (char*)d_ws;

    const int B = 2, S = 2048, H = 4096, NQ = 4352;
    const int M = B * S;

    unsigned short* hb  = (unsigned short*)(ws);                            // 32 MB: hidden bf16, later attn out
    unsigned short* wT  = (unsigned short*)(ws + 33554432);                 // 35.7 MB: WqkvT, later WoT
    unsigned short* qkv = (unsigned short*)(ws + 33554432 + 35651584);      // 35.7 MB: qkv bf16

    cast_bf16_kernel<<<(M * H / 8) / 256, 256, 0, stream>>>(hidden, hb, M * H / 8);
    transpose_cast_kernel<<<dim3(NQ / 32, H / 32), 256, 0, stream>>>(Wqkv, wT, H, NQ);
    gemm_kernel<1><<<dim3(NQ / 128, M / 128), 256, 0, stream>>>(hb, wT, qkv, M, NQ, H);
    transpose_cast_kernel<<<dim3(H / 32, H / 32), 256, 0, stream>>>(Wo, wT, H, H);
    attn_kernel<<<dim3(S / 64, 32, B), 256, 0, stream>>>(qkv, hb, S);
    gemm_kernel<0><<<dim3(H / 128, M / 128), 256, 0, stream>>>(hb, wT, out, M, H, H);
}

// Round 3
// 618.050 us; speedup vs baseline: 1.6266x; 1.6266x over previous
//
#include <hip/hip_runtime.h>
#include <hip/hip_bf16.h>

// ---------- types ----------
typedef __attribute__((ext_vector_type(8))) short bf16x8;
typedef __attribute__((ext_vector_type(4))) float f32x4;
typedef __attribute__((ext_vector_type(8))) unsigned short u16x8;

__device__ __forceinline__ unsigned short f2bf(float x) {
    union { float f; unsigned u; } v; v.f = x;
    unsigned r = v.u + 0x7fff + ((v.u >> 16) & 1);   // RNE
    return (unsigned short)(r >> 16);
}

__device__ __forceinline__ void gload16(const void* g, void* l) {
    __builtin_amdgcn_global_load_lds(
        (const __attribute__((address_space(1))) void*)g,
        (__attribute__((address_space(3))) void*)l, 16, 0, 0);
}

// ---------- cast fp32 -> bf16, 8 elems/thread ----------
__global__ __launch_bounds__(256) void cast_bf16_kernel(
    const float* __restrict__ src, unsigned short* __restrict__ dst, int n8) {
    int i = blockIdx.x * 256 + threadIdx.x;
    if (i >= n8) return;
    const float4* s = (const float4*)src + (size_t)i * 2;
    float4 a = s[0], b = s[1];
    u16x8 o;
    o[0] = f2bf(a.x); o[1] = f2bf(a.y); o[2] = f2bf(a.z); o[3] = f2bf(a.w);
    o[4] = f2bf(b.x); o[5] = f2bf(b.y); o[6] = f2bf(b.z); o[7] = f2bf(b.w);
    *(u16x8*)(dst + (size_t)i * 8) = o;
}

// ---------- transpose + cast: src fp32 [R][C] -> dst bf16 [C][R] ----------
__global__ __launch_bounds__(256) void transpose_cast_kernel(
    const float* __restrict__ src, unsigned short* __restrict__ dst, int R, int C) {
    __shared__ float tile[32][33];
    const int bx = blockIdx.x * 32, by = blockIdx.y * 32;
    const int tx = threadIdx.x & 31, ty = threadIdx.x >> 5;  // 32 x 8
#pragma unroll
    for (int i = 0; i < 32; i += 8)
        tile[ty + i][tx] = src[(size_t)(by + ty + i) * C + (bx + tx)];
    __syncthreads();
#pragma unroll
    for (int i = 0; i < 32; i += 8)
        dst[(size_t)(bx + ty + i) * R + (by + tx)] = f2bf(tile[tx][ty + i]);
}

// ---------- GEMM: C[M][N] = A[M][K](bf16) @ BT[N][K](bf16)^T ----------
template <int OUTBF>
__global__ __launch_bounds__(256) void gemm_kernel(
    const unsigned short* __restrict__ A, const unsigned short* __restrict__ BT,
    void* __restrict__ Cp, int M, int N, int K) {
    __shared__ unsigned short Al[2][128 * 32];
    __shared__ unsigned short Bl[2][128 * 32];
    const int t = threadIdx.x;
    const int wid = t >> 6, lane = t & 63;
    const int l15 = lane & 15, lg = lane >> 4;
    const int bm = blockIdx.y * 128, bn = blockIdx.x * 128;
    const int wm = (wid >> 1) * 64, wn = (wid & 1) * 64;

    f32x4 acc[4][4];
#pragma unroll
    for (int i = 0; i < 4; ++i)
#pragma unroll
        for (int j = 0; j < 4; ++j) acc[i][j] = (f32x4)(0.f);

    const int nk = K >> 5;
    const int c0 = t, c1 = t + 256;

    auto stage = [&](int buf, int kt) {
        const unsigned short* Ab = A + (size_t)bm * K + kt * 32;
        const unsigned short* Bb = BT + (size_t)bn * K + kt * 32;
        gload16(Ab + (size_t)(c0 >> 2) * K + (c0 & 3) * 8, &Al[buf][wid * 64 * 8]);
        gload16(Ab + (size_t)(c1 >> 2) * K + (c1 & 3) * 8, &Al[buf][(256 + wid * 64) * 8]);
        gload16(Bb + (size_t)(c0 >> 2) * K + (c0 & 3) * 8, &Bl[buf][wid * 64 * 8]);
        gload16(Bb + (size_t)(c1 >> 2) * K + (c1 & 3) * 8, &Bl[buf][(256 + wid * 64) * 8]);
    };

    stage(0, 0);
    __syncthreads();
    for (int kt = 0; kt < nk; ++kt) {
        const int cur = kt & 1;
        if (kt + 1 < nk) stage(cur ^ 1, kt + 1);
        bf16x8 af[4], bfr[4];
#pragma unroll
        for (int i = 0; i < 4; ++i) {
            af[i]  = *(const bf16x8*)&Al[cur][(wm + i * 16 + l15) * 32 + lg * 8];
            bfr[i] = *(const bf16x8*)&Bl[cur][(wn + i * 16 + l15) * 32 + lg * 8];
        }
#pragma unroll
        for (int i = 0; i < 4; ++i)
#pragma unroll
            for (int j = 0; j < 4; ++j)
                acc[i][j] = __builtin_amdgcn_mfma_f32_16x16x32_bf16(af[i], bfr[j], acc[i][j], 0, 0, 0);
        __syncthreads();
    }

#pragma unroll
    for (int i = 0; i < 4; ++i)
#pragma unroll
        for (int j = 0; j < 4; ++j)
#pragma unroll
            for (int r = 0; r < 4; ++r) {
                const int row = bm + wm + i * 16 + lg * 4 + r;
                const int col = bn + wn + j * 16 + l15;
                if (OUTBF) ((unsigned short*)Cp)[(size_t)row * N + col] = f2bf(acc[i][j][r]);
                else       ((float*)Cp)[(size_t)row * N + col] = acc[i][j][r];
            }
}

// ---------- flash attention v3 (MQA, ALiBi, causal) ----------
// Balanced causal pairing: block p handles q-blocks {p, 31-p} (33 KV64-tiles).
// 4 waves; wave w owns q rows qblk*64 + w*16 .. +15. KVBLK=64.
// K : LDS [64][128] elems, XOR-swizzled byte^=(row&7)<<4, staged via gload16
//     with pre-swizzled global source (rule #21 both-sides pattern).
// V^T: LDS [128][64] elems (128B rows), byte^=(dd&7)<<4; manual reg transpose,
//     lane = kv row, wave = 32-d block -> each wave store hits 32 words 2-way.
// P : per-wave LDS [16 rows][128B], byte^=(row&7)<<4.
__global__ __launch_bounds__(256, 4) void attn_kernel(
    const unsigned short* __restrict__ qkv, unsigned short* __restrict__ attn, int S) {
    constexpr int LD = 4352;
    __shared__ unsigned short Kl[64 * 128];
    __shared__ unsigned short Vt[128 * 64];
    __shared__ unsigned short Pl[4][16 * 64];
    const int t = threadIdx.x, wid = t >> 6;
    const int lane = t & 63, l15 = lane & 15, lg = lane >> 4;
    const int h = blockIdx.y, b = blockIdx.z;
    const size_t rb = (size_t)b * S;
    const int nQB = S >> 6;                       // 32
    const float scale2 = 0.08838834764831845f * 1.4426950408889634f;
    const float slope2 = exp2f(-0.25f * (float)(h + 1)) * 1.4426950408889634f;

    for (int half = 0; half < 2; ++half) {
        const int qblk = half ? (nQB - 1 - (int)blockIdx.x) : (int)blockIdx.x;
        const int q0 = qblk * 64 + wid * 16;

        bf16x8 qf[4];
        {
            const unsigned short* qrow = qkv + (rb + q0 + l15) * LD + h * 128 + lg * 8;
#pragma unroll
            for (int j = 0; j < 4; ++j) qf[j] = *(const bf16x8*)(qrow + j * 32);
        }
        f32x4 o[8];
#pragma unroll
        for (int i = 0; i < 8; ++i) o[i] = (f32x4)(0.f);
        float m_[4], l_[4];
#pragma unroll
        for (int r = 0; r < 4; ++r) { m_[r] = -1e30f; l_[r] = 0.f; }

        const int ntile = qblk + 1;
        for (int tile = 0; tile < ntile; ++tile) {
            const int t0 = tile * 64;
            // ---- stage K (gload16, pre-swizzled source) ----
            {
                const char* kbase = (const char*)(qkv + (rb + t0) * LD + 4096);
#pragma unroll
                for (int i = 0; i < 4; ++i) {
                    const int c = i * 256 + t;
                    const int krow = c >> 4;
                    gload16(kbase + (size_t)krow * (LD * 2) + (((c & 15) * 16) ^ ((krow & 7) << 4)),
                            (char*)Kl + (i * 256 + wid * 64) * 16);
                }
            }
            // ---- stage V^T: lane = kv row, wave = 32-wide d block ----
            {
                const unsigned short* vs = qkv + (rb + t0 + lane) * LD + 4224 + wid * 32;
                u16x8 v0 = *(const u16x8*)vs;
                u16x8 v1 = *(const u16x8*)(vs + 8);
                u16x8 v2 = *(const u16x8*)(vs + 16);
                u16x8 v3 = *(const u16x8*)(vs + 24);
                const int kb = 2 * lane;
#pragma unroll
                for (int e = 0; e < 8; ++e) {
                    int dd = wid * 32 + e;
                    *(unsigned short*)((char*)Vt + dd * 128 + (kb ^ ((dd & 7) << 4))) = v0[e];
                    dd += 8;
                    *(unsigned short*)((char*)Vt + dd * 128 + (kb ^ ((dd & 7) << 4))) = v1[e];
                    dd += 8;
                    *(unsigned short*)((char*)Vt + dd * 128 + (kb ^ ((dd & 7) << 4))) = v2[e];
                    dd += 8;
                    *(unsigned short*)((char*)Vt + dd * 128 + (kb ^ ((dd & 7) << 4))) = v3[e];
                }
            }
            __syncthreads();

            // ---- QK^T: 4 col-tiles of 16 ----
            f32x4 s4[4];
#pragma unroll
            for (int ct = 0; ct < 4; ++ct) {
                s4[ct] = (f32x4)(0.f);
                const int row = ct * 16 + l15;
                const int swz = (row & 7) << 4;
#pragma unroll
                for (int j = 0; j < 4; ++j) {
                    bf16x8 kf = *(const bf16x8*)((const char*)Kl + row * 256 +
                                                 ((j * 64 + lg * 16) ^ swz));
                    s4[ct] = __builtin_amdgcn_mfma_f32_16x16x32_bf16(qf[j], kf, s4[ct], 0, 0, 0);
                }
            }

            // ---- online softmax (log2 domain), rows q = q0 + lg*4 + r ----
            float corr[4];
#pragma unroll
            for (int r = 0; r < 4; ++r) {
                const int q = q0 + lg * 4 + r;
                float sc[4];
#pragma unroll
                for (int ct = 0; ct < 4; ++ct) {
                    const int kv = t0 + ct * 16 + l15;
                    sc[ct] = (kv <= q) ? s4[ct][r] * scale2 + slope2 * (float)(kv - q) : -1e30f;
                }
                float mx = fmaxf(fmaxf(sc[0], sc[1]), fmaxf(sc[2], sc[3]));
                mx = fmaxf(mx, __shfl_xor(mx, 1, 16));
                mx = fmaxf(mx, __shfl_xor(mx, 2, 16));
                mx = fmaxf(mx, __shfl_xor(mx, 4, 16));
                mx = fmaxf(mx, __shfl_xor(mx, 8, 16));
                const float mnew = fmaxf(m_[r], mx);
                corr[r] = exp2f(m_[r] - mnew);
                m_[r] = mnew;
                float p0 = exp2f(sc[0] - mnew), p1 = exp2f(sc[1] - mnew);
                float p2 = exp2f(sc[2] - mnew), p3 = exp2f(sc[3] - mnew);
                float rs = (p0 + p1) + (p2 + p3);
                rs += __shfl_xor(rs, 1, 16);
                rs += __shfl_xor(rs, 2, 16);
                rs += __shfl_xor(rs, 4, 16);
                rs += __shfl_xor(rs, 8, 16);
                l_[r] = l_[r] * corr[r] + rs;
                const int prow = lg * 4 + r;
                char* pb = (char*)&Pl[wid][0] + prow * 128;
                const int swz = (prow & 7) << 4;
                *(unsigned short*)(pb + ((2 * l15) ^ swz))      = f2bf(p0);
                *(unsigned short*)(pb + ((32 + 2 * l15) ^ swz)) = f2bf(p1);
                *(unsigned short*)(pb + ((64 + 2 * l15) ^ swz)) = f2bf(p2);
                *(unsigned short*)(pb + ((96 + 2 * l15) ^ swz)) = f2bf(p3);
            }

            // ---- PV: O += P @ V  (A from Pl, B from Vt rows) ----
            const char* pb = (const char*)&Pl[wid][0] + l15 * 128;
            const int pswz = (l15 & 7) << 4;
            bf16x8 pa0 = *(const bf16x8*)(pb + ((lg * 16) ^ pswz));
            bf16x8 pa1 = *(const bf16x8*)(pb + ((64 + lg * 16) ^ pswz));
#pragma unroll
            for (int n = 0; n < 8; ++n) {
                const int dd = n * 16 + l15;
                const int vswz = (dd & 7) << 4;
                bf16x8 vf0 = *(const bf16x8*)((const char*)Vt + dd * 128 + ((lg * 16) ^ vswz));
                bf16x8 vf1 = *(const bf16x8*)((const char*)Vt + dd * 128 + ((64 + lg * 16) ^ vswz));
                f32x4 a4 = o[n];
                a4[0] *= corr[0]; a4[1] *= corr[1]; a4[2] *= corr[2]; a4[3] *= corr[3];
                a4 = __builtin_amdgcn_mfma_f32_16x16x32_bf16(pa0, vf0, a4, 0, 0, 0);
                a4 = __builtin_amdgcn_mfma_f32_16x16x32_bf16(pa1, vf1, a4, 0, 0, 0);
                o[n] = a4;
            }
            __syncthreads();
        }

        // ---- epilogue ----
        float rinv[4];
#pragma unroll
        for (int r = 0; r < 4; ++r) rinv[r] = 1.f / l_[r];
#pragma unroll
        for (int n = 0; n < 8; ++n)
#pragma unroll
            for (int r = 0; r < 4; ++r) {
                const int q = q0 + lg * 4 + r;
                attn[(rb + q) * 4096 + h * 128 + n * 16 + l15] = f2bf(o[n][r] * rinv[r]);
            }
    }
}

// ---------- launch ----------
extern "C" void kernel_launch(void* const* d_in, const int* in_sizes, int n_in,
                              void* d_out, int out_size, void* d_ws, size_t ws_size,
                              hipStream_t stream) {
    const float* hidden = (const float*)d_in[0];
    const float* Wqkv   = (const float*)d_in[1];
    const float* Wo     = (const float*)d_in[2];
    float* out = (float*)d_out;
    char* ws = (char*)d_ws;

    const int B = 2, S = 2048, H = 4096, NQ = 4352;
    const int M = B * S;

    unsigned short* hb  = (unsigned short*)(ws);                            // hidden bf16, later attn out
    unsigned short* wT  = (unsigned short*)(ws + 33554432);                 // WqkvT, later WoT
    unsigned short* qkv = (unsigned short*)(ws + 33554432 + 35651584);      // qkv bf16

    cast_bf16_kernel<<<(M * H / 8) / 256, 256, 0, stream>>>(hidden, hb, M * H / 8);
    transpose_cast_kernel<<<dim3(NQ / 32, H / 32), 256, 0, stream>>>(Wqkv, wT, H, NQ);
    gemm_kernel<1><<<dim3(NQ / 128, M / 128), 256, 0, stream>>>(hb, wT, qkv, M, NQ, H);
    transpose_cast_kernel<<<dim3(H / 32, H / 32), 256, 0, stream>>>(Wo, wT, H, H);
    attn_kernel<<<dim3(16, 32, 2), 256, 0, stream>>>(qkv, hb, S);
    gemm_kernel<0><<<dim3(H / 128, M / 128), 256, 0, stream>>>(hb, wT, out, M, H, H);
}

// Round 4
// 555.354 us; speedup vs baseline: 1.8102x; 1.1129x over previous
//
#include <hip/hip_runtime.h>
#include <hip/hip_bf16.h>

// ---------- types ----------
typedef __attribute__((ext_vector_type(8))) short bf16x8;
typedef __attribute__((ext_vector_type(4))) float f32x4;
typedef __attribute__((ext_vector_type(8))) unsigned short u16x8;
typedef __attribute__((ext_vector_type(4))) unsigned short u16x4;

__device__ __forceinline__ unsigned short f2bf(float x) {
    union { float f; unsigned u; } v; v.f = x;
    unsigned r = v.u + 0x7fff + ((v.u >> 16) & 1);   // RNE
    return (unsigned short)(r >> 16);
}

__device__ __forceinline__ unsigned short f2bf_hw(float x) {
    __hip_bfloat16 h = __float2bfloat16(x);
    return *reinterpret_cast<unsigned short*>(&h);
}

__device__ __forceinline__ void gload16(const void* g, void* l) {
    __builtin_amdgcn_global_load_lds(
        (const __attribute__((address_space(1))) void*)g,
        (__attribute__((address_space(3))) void*)l, 16, 0, 0);
}

// ---------- cast fp32 -> bf16, 8 elems/thread ----------
__global__ __launch_bounds__(256) void cast_bf16_kernel(
    const float* __restrict__ src, unsigned short* __restrict__ dst, int n8) {
    int i = blockIdx.x * 256 + threadIdx.x;
    if (i >= n8) return;
    const float4* s = (const float4*)src + (size_t)i * 2;
    float4 a = s[0], b = s[1];
    u16x8 o;
    o[0] = f2bf(a.x); o[1] = f2bf(a.y); o[2] = f2bf(a.z); o[3] = f2bf(a.w);
    o[4] = f2bf(b.x); o[5] = f2bf(b.y); o[6] = f2bf(b.z); o[7] = f2bf(b.w);
    *(u16x8*)(dst + (size_t)i * 8) = o;
}

// ---------- transpose + cast: src fp32 [R][C] -> dst bf16 [C][R] ----------
__global__ __launch_bounds__(256) void transpose_cast_kernel(
    const float* __restrict__ src, unsigned short* __restrict__ dst, int R, int C) {
    __shared__ float tile[32][33];
    const int bx = blockIdx.x * 32, by = blockIdx.y * 32;
    const int tx = threadIdx.x & 31, ty = threadIdx.x >> 5;  // 32 x 8
#pragma unroll
    for (int i = 0; i < 32; i += 8)
        tile[ty + i][tx] = src[(size_t)(by + ty + i) * C + (bx + tx)];
    __syncthreads();
#pragma unroll
    for (int i = 0; i < 32; i += 8)
        dst[(size_t)(bx + ty + i) * R + (by + tx)] = f2bf(tile[tx][ty + i]);
}

// ---------- GEMM: C[M][N] = A[M][K](bf16) @ BT[N][K](bf16)^T ----------
template <int OUTBF>
__global__ __launch_bounds__(256) void gemm_kernel(
    const unsigned short* __restrict__ A, const unsigned short* __restrict__ BT,
    void* __restrict__ Cp, int M, int N, int K) {
    __shared__ unsigned short Al[2][128 * 32];
    __shared__ unsigned short Bl[2][128 * 32];
    const int t = threadIdx.x;
    const int wid = t >> 6, lane = t & 63;
    const int l15 = lane & 15, lg = lane >> 4;
    const int bm = blockIdx.y * 128, bn = blockIdx.x * 128;
    const int wm = (wid >> 1) * 64, wn = (wid & 1) * 64;

    f32x4 acc[4][4];
#pragma unroll
    for (int i = 0; i < 4; ++i)
#pragma unroll
        for (int j = 0; j < 4; ++j) acc[i][j] = (f32x4)(0.f);

    const int nk = K >> 5;
    const int c0 = t, c1 = t + 256;

    auto stage = [&](int buf, int kt) {
        const unsigned short* Ab = A + (size_t)bm * K + kt * 32;
        const unsigned short* Bb = BT + (size_t)bn * K + kt * 32;
        gload16(Ab + (size_t)(c0 >> 2) * K + (c0 & 3) * 8, &Al[buf][wid * 64 * 8]);
        gload16(Ab + (size_t)(c1 >> 2) * K + (c1 & 3) * 8, &Al[buf][(256 + wid * 64) * 8]);
        gload16(Bb + (size_t)(c0 >> 2) * K + (c0 & 3) * 8, &Bl[buf][wid * 64 * 8]);
        gload16(Bb + (size_t)(c1 >> 2) * K + (c1 & 3) * 8, &Bl[buf][(256 + wid * 64) * 8]);
    };

    stage(0, 0);
    __syncthreads();
    for (int kt = 0; kt < nk; ++kt) {
        const int cur = kt & 1;
        if (kt + 1 < nk) stage(cur ^ 1, kt + 1);
        bf16x8 af[4], bfr[4];
#pragma unroll
        for (int i = 0; i < 4; ++i) {
            af[i]  = *(const bf16x8*)&Al[cur][(wm + i * 16 + l15) * 32 + lg * 8];
            bfr[i] = *(const bf16x8*)&Bl[cur][(wn + i * 16 + l15) * 32 + lg * 8];
        }
#pragma unroll
        for (int i = 0; i < 4; ++i)
#pragma unroll
            for (int j = 0; j < 4; ++j)
                acc[i][j] = __builtin_amdgcn_mfma_f32_16x16x32_bf16(af[i], bfr[j], acc[i][j], 0, 0, 0);
        __syncthreads();
    }

#pragma unroll
    for (int i = 0; i < 4; ++i)
#pragma unroll
        for (int j = 0; j < 4; ++j)
#pragma unroll
            for (int r = 0; r < 4; ++r) {
                const int row = bm + wm + i * 16 + lg * 4 + r;
                const int col = bn + wn + j * 16 + l15;
                if (OUTBF) ((unsigned short*)Cp)[(size_t)row * N + col] = f2bf(acc[i][j][r]);
                else       ((float*)Cp)[(size_t)row * N + col] = acc[i][j][r];
            }
}

// ---------- flash attention v4 (MQA, ALiBi, causal, swapped-QK softmax) ----------
// Balanced causal pairing: block p handles q-blocks {p, 31-p} (33 KV64-tiles).
// 4 waves; wave w owns q rows qblk*64 + w*16 .. +15. KVBLK=64.
// QK^T computed SWAPPED: mfma(K, Q) -> D[row=kv][col=q]; each lane owns one
//   q-row (q = q0w + l15) x 16 kv entries -> in-lane softmax, 4 shfl_xor total.
// K : LDS [64][128], byte^=(row&7)<<4, staged via gload16 w/ pre-swizzled src.
// V^T: LDS [128][64] 128B rows, byte^=(dd&7)<<4, manual reg transpose.
// P : per-wave LDS [16 q][64 kv] 128B rows, byte^=(q&7)<<4, 4x ds_write_b64.
__global__ __launch_bounds__(256, 4) void attn_kernel(
    const unsigned short* __restrict__ qkv, unsigned short* __restrict__ attn, int S) {
    constexpr int LD = 4352;
    __shared__ unsigned short Kl[64 * 128];
    __shared__ unsigned short Vt[128 * 64];
    __shared__ unsigned short Pl[4][16 * 64];
    const int t = threadIdx.x, wid = t >> 6;
    const int lane = t & 63, l15 = lane & 15, lg = lane >> 4;
    const int h = blockIdx.y, b = blockIdx.z;
    const size_t rb = (size_t)b * S;
    const int nQB = S >> 6;                       // 32
    const float scale2 = 0.08838834764831845f * 1.4426950408889634f;
    const float slope2 = exp2f(-0.25f * (float)(h + 1)) * 1.4426950408889634f;
    const float sr1 = slope2, sr2 = slope2 * 2.f, sr3 = slope2 * 3.f;

    for (int half = 0; half < 2; ++half) {
        const int qblk = half ? (nQB - 1 - (int)blockIdx.x) : (int)blockIdx.x;
        const int q0w = qblk * 64 + wid * 16;
        const int qlane = q0w + l15;              // this lane's q-row for softmax
        const float aq = slope2 * (float)qlane;

        bf16x8 qf[4];
        {
            const unsigned short* qrow = qkv + (rb + qlane) * LD + h * 128 + lg * 8;
#pragma unroll
            for (int j = 0; j < 4; ++j) qf[j] = *(const bf16x8*)(qrow + j * 32);
        }
        f32x4 o[8];
#pragma unroll
        for (int i = 0; i < 8; ++i) o[i] = (f32x4)(0.f);
        float m_ = -1e30f, l_ = 0.f;

        const int ntile = qblk + 1;
        for (int tile = 0; tile < ntile; ++tile) {
            const int t0 = tile * 64;
            // ---- stage K (gload16, pre-swizzled source) ----
            {
                const char* kbase = (const char*)(qkv + (rb + t0) * LD + 4096);
#pragma unroll
                for (int i = 0; i < 4; ++i) {
                    const int c = i * 256 + t;
                    const int krow = c >> 4;
                    gload16(kbase + (size_t)krow * (LD * 2) + (((c & 15) * 16) ^ ((krow & 7) << 4)),
                            (char*)Kl + (i * 256 + wid * 64) * 16);
                }
            }
            // ---- stage V^T: lane = kv row, wave = 32-wide d block ----
            {
                const unsigned short* vs = qkv + (rb + t0 + lane) * LD + 4224 + wid * 32;
                u16x8 v0 = *(const u16x8*)vs;
                u16x8 v1 = *(const u16x8*)(vs + 8);
                u16x8 v2 = *(const u16x8*)(vs + 16);
                u16x8 v3 = *(const u16x8*)(vs + 24);
                const int kb = 2 * lane;
#pragma unroll
                for (int e = 0; e < 8; ++e) {
                    int dd = wid * 32 + e;
                    *(unsigned short*)((char*)Vt + dd * 128 + (kb ^ ((dd & 7) << 4))) = v0[e];
                    dd += 8;
                    *(unsigned short*)((char*)Vt + dd * 128 + (kb ^ ((dd & 7) << 4))) = v1[e];
                    dd += 8;
                    *(unsigned short*)((char*)Vt + dd * 128 + (kb ^ ((dd & 7) << 4))) = v2[e];
                    dd += 8;
                    *(unsigned short*)((char*)Vt + dd * 128 + (kb ^ ((dd & 7) << 4))) = v3[e];
                }
            }
            __syncthreads();

            // ---- QK^T SWAPPED: D[row=kv (lg*4+r within ct-block)][col=q (l15)] ----
            f32x4 s4[4];
#pragma unroll
            for (int ct = 0; ct < 4; ++ct) {
                s4[ct] = (f32x4)(0.f);
                const int row = ct * 16 + l15;
                const int swz = (row & 7) << 4;
#pragma unroll
                for (int j = 0; j < 4; ++j) {
                    bf16x8 kf = *(const bf16x8*)((const char*)Kl + row * 256 +
                                                 ((j * 64 + lg * 16) ^ swz));
                    s4[ct] = __builtin_amdgcn_mfma_f32_16x16x32_bf16(kf, qf[j], s4[ct], 0, 0, 0);
                }
            }

            // ---- in-lane online softmax (log2 domain); lane owns q = qlane ----
            const float base = slope2 * (float)(t0 + lg * 4) - aq;
            float p4[4][4];
            float mx = -1e30f;
            const bool lastt = (tile == ntile - 1);
            const int dbase = t0 + lg * 4 - qlane;
#pragma unroll
            for (int ct = 0; ct < 4; ++ct) {
                const float bbc = base + slope2 * 16.f * (float)ct;
#pragma unroll
                for (int r = 0; r < 4; ++r) {
                    float sc = fmaf(s4[ct][r], scale2,
                                    bbc + (r == 0 ? 0.f : (r == 1 ? sr1 : (r == 2 ? sr2 : sr3))));
                    if (lastt && (dbase + ct * 16 + r > 0)) sc = -1e30f;
                    p4[ct][r] = sc;
                    mx = fmaxf(mx, sc);
                }
            }
            mx = fmaxf(mx, __shfl_xor(mx, 16));
            mx = fmaxf(mx, __shfl_xor(mx, 32));

            // defer-max (T13): rescale only if some row grew > 8 (log2)
            if (!__all(mx <= m_ + 8.0f)) {
                const float mnew = fmaxf(m_, mx);
                const float corr = exp2f(m_ - mnew);
                m_ = mnew;
                l_ *= corr;
                float cr[4];
#pragma unroll
                for (int r = 0; r < 4; ++r) cr[r] = __shfl(corr, lg * 4 + r);
#pragma unroll
                for (int n = 0; n < 8; ++n) {
                    o[n][0] *= cr[0]; o[n][1] *= cr[1];
                    o[n][2] *= cr[2]; o[n][3] *= cr[3];
                }
            }

            float rs = 0.f;
#pragma unroll
            for (int ct = 0; ct < 4; ++ct)
#pragma unroll
                for (int r = 0; r < 4; ++r) {
                    const float pv = exp2f(p4[ct][r] - m_);
                    p4[ct][r] = pv;
                    rs += pv;
                }
            rs += __shfl_xor(rs, 16);
            rs += __shfl_xor(rs, 32);
            l_ += rs;

            // ---- P store: lane writes row q=l15, kv cols ct*16+lg*4 .. +3 ----
            {
                char* pb = (char*)&Pl[wid][0] + l15 * 128;
                const int swz = (l15 & 7) << 4;
#pragma unroll
                for (int ct = 0; ct < 4; ++ct) {
                    u16x4 w;
                    w[0] = f2bf_hw(p4[ct][0]); w[1] = f2bf_hw(p4[ct][1]);
                    w[2] = f2bf_hw(p4[ct][2]); w[3] = f2bf_hw(p4[ct][3]);
                    *(u16x4*)(pb + ((ct * 32 + lg * 8) ^ swz)) = w;
                }
            }

            // ---- PV: O += P @ V  (corr already applied to o) ----
            const char* pb = (const char*)&Pl[wid][0] + l15 * 128;
            const int pswz = (l15 & 7) << 4;
            bf16x8 pa0 = *(const bf16x8*)(pb + ((lg * 16) ^ pswz));
            bf16x8 pa1 = *(const bf16x8*)(pb + ((64 + lg * 16) ^ pswz));
#pragma unroll
            for (int n = 0; n < 8; ++n) {
                const int dd = n * 16 + l15;
                const int vswz = (dd & 7) << 4;
                bf16x8 vf0 = *(const bf16x8*)((const char*)Vt + dd * 128 + ((lg * 16) ^ vswz));
                bf16x8 vf1 = *(const bf16x8*)((const char*)Vt + dd * 128 + ((64 + lg * 16) ^ vswz));
                f32x4 a4 = __builtin_amdgcn_mfma_f32_16x16x32_bf16(pa0, vf0, o[n], 0, 0, 0);
                o[n] = __builtin_amdgcn_mfma_f32_16x16x32_bf16(pa1, vf1, a4, 0, 0, 0);
            }
            __syncthreads();
        }

        // ---- epilogue: rinv lives on lane l15=q; broadcast to o-rows ----
        const float rl = 1.f / l_;
        float rv[4];
#pragma unroll
        for (int r = 0; r < 4; ++r) rv[r] = __shfl(rl, lg * 4 + r);
#pragma unroll
        for (int n = 0; n < 8; ++n)
#pragma unroll
            for (int r = 0; r < 4; ++r) {
                const int q = q0w + lg * 4 + r;
                attn[(rb + q) * 4096 + h * 128 + n * 16 + l15] = f2bf(o[n][r] * rv[r]);
            }
    }
}

// ---------- launch ----------
extern "C" void kernel_launch(void* const* d_in, const int* in_sizes, int n_in,
                              void* d_out, int out_size, void* d_ws, size_t ws_size,
                              hipStream_t stream) {
    const float* hidden = (const float*)d_in[0];
    const float* Wqkv   = (const float*)d_in[1];
    const float* Wo     = (const float*)d_in[2];
    float* out = (float*)d_out;
    char* ws = (char*)d_ws;

    const int B = 2, S = 2048, H = 4096, NQ = 4352;
    const int M = B * S;

    unsigned short* hb  = (unsigned short*)(ws);                            // hidden bf16, later attn out
    unsigned short* wT  = (unsigned short*)(ws + 33554432);                 // WqkvT, later WoT
    unsigned short* qkv = (unsigned short*)(ws + 33554432 + 35651584);      // qkv bf16

    cast_bf16_kernel<<<(M * H / 8) / 256, 256, 0, stream>>>(hidden, hb, M * H / 8);
    transpose_cast_kernel<<<dim3(NQ / 32, H / 32), 256, 0, stream>>>(Wqkv, wT, H, NQ);
    gemm_kernel<1><<<dim3(NQ / 128, M / 128), 256, 0, stream>>>(hb, wT, qkv, M, NQ, H);
    transpose_cast_kernel<<<dim3(H / 32, H / 32), 256, 0, stream>>>(Wo, wT, H, H);
    attn_kernel<<<dim3(16, 32, 2), 256, 0, stream>>>(qkv, hb, S);
    gemm_kernel<0><<<dim3(H / 128, M / 128), 256, 0, stream>>>(hb, wT, out, M, H, H);
}